// Round 11
// baseline (141.845 us; speedup 1.0000x reference)
//
#include <hip/hip_runtime.h>

// RetrosynthesisAttention, B=16, N=M=D=U=256, fp32 — split-phase build:
//   split_kernel : one-shot bf16 hi/lo decomposition of X=[enc;dec] and W^T
//   proj_kernel  : MFMA bf16 3-pass GEMMs, staging = pure bf16 copies
//   logit_kernel : r7 body, m-split x2 (256 thr, 8n x 128m, 1024 blocks)
//   smctx_kernel : r7 VERBATIM
//
// Math: tanh(x) = 1 - 2/(exp2(Kx)+1); constants cancel in softmax.
// z_u = rcpc(v_u)*2^-16 + E'_u*(D_u*rcpc(v_u)); sum 1/z over 8 u's per v_rcp.
// Proj: A=Ah+Al, W=Wh+Wl (bf16 truncation), Ah*Wh+Ah*Wl+Al*Wh in fp32 acc.
// MFMA 16x16x32_bf16 layouts (m89-verified): A r=lane&15,k=(lane>>4)*8+j;
// B c=lane&15 (from W^T planes); D c=lane&15, r=(lane>>4)*4+reg.

constexpr float KSC   = 2.8853900817779268f;   // 2*log2(e)
constexpr float LOG2E = 1.4426950408889634f;
constexpr float S16   = 1.52587890625e-05f;    // 2^-16
constexpr float LSC   = -3.0517578125e-05f;    // -2^-15

struct F4 { float v[4]; };
__device__ __forceinline__ F4 ld4(const float* p) {
    float4 t = *(const float4*)p;
    F4 r; r.v[0] = t.x; r.v[1] = t.y; r.v[2] = t.z; r.v[3] = t.w; return r;
}
__device__ __forceinline__ float rcp_clamp(float v) {
    float r = __builtin_amdgcn_rcpf(v);
    return fminf(fmaxf(r, -1e4f), 1e4f);   // identical in all kernels
}

typedef __attribute__((ext_vector_type(8))) short bf16x8;
typedef __attribute__((ext_vector_type(4))) float f32x4;

// ---------------- Kernel 0: bf16 hi/lo split pre-pass.
// X: flat rows 0..8191 ([enc;dec]) -> Xh/Xl [8192][256] (coalesced).
// W1/W2 -> W^T hi/lo [2][256u][256k] (scattered 2B writes, tiny volume).
__global__ __launch_bounds__(256) void split_kernel(
    const float* __restrict__ enc, const float* __restrict__ dec,
    const float* __restrict__ W1,  const float* __restrict__ W2,
    short* __restrict__ Xh, short* __restrict__ Xl,
    short* __restrict__ WTh, short* __restrict__ WTl)
{
    const int idx = blockIdx.x * 256 + threadIdx.x;
    if (idx < 2097152) {
        const int row = idx >> 8, k = idx & 255;
        const float x = (row < 4096) ? enc[row * 256 + k]
                                     : dec[(row - 4096) * 256 + k];
        const unsigned bx = __float_as_uint(x);
        const float fh = __uint_as_float(bx & 0xFFFF0000u);
        Xh[idx] = (short)(bx >> 16);
        Xl[idx] = (short)(__float_as_uint(x - fh) >> 16);
    } else {
        const int f2 = idx - 2097152;        // 0..131071
        const int t = f2 >> 16, r = f2 & 65535;
        const int k = r >> 8, u = r & 255;   // read W[k][u] coalesced over u
        const float x = (t ? W2 : W1)[k * 256 + u];
        const unsigned bx = __float_as_uint(x);
        const float fh = __uint_as_float(bx & 0xFFFF0000u);
        const int o = t * 65536 + u * 256 + k;   // transposed [u][k]
        WTh[o] = (short)(bx >> 16);
        WTl[o] = (short)(__float_as_uint(x - fh) >> 16);
    }
}

// ---------------- Kernel 1: MFMA projection GEMMs + exp2 epilogue.
// Block 256 thr = 4 waves (2x2 of 32x32 wave-tiles) = 64 rows x 64 u, K-step
// 32. Staging = direct bf16x8 copies from precomputed planes (no split math).
// Pad 40 shorts (80B rows: 16B-aligned b128, 2-way banks = free).
__global__ __launch_bounds__(256) void proj_kernel(
    const short* __restrict__ Xh, const short* __restrict__ Xl,
    const short* __restrict__ WTh, const short* __restrict__ WTl,
    const float* __restrict__ b1, const float* __restrict__ b2,
    const float* __restrict__ vw,
    float* __restrict__ encQ, float* __restrict__ decE)
{
    __shared__ __align__(16) short Ah[64][40], Al[64][40];   // [row][k]
    __shared__ __align__(16) short Bh[64][40], Bl[64][40];   // [u][k]

    const int tid  = threadIdx.x;
    const int lane = tid & 63;
    const int wv   = tid >> 6;          // 0..3
    const int wr   = wv >> 1, wc = wv & 1;
    const int u0   = blockIdx.x << 6;   // 0,64,128,192
    const int rblk = blockIdx.y;        // 0..127 over 8192 flat rows
    const bool is_enc = rblk < 64;
    const int rbf = rblk << 6;          // flat row base (Xh/Xl indexing)
    const int rbt = rbf & 4095;         // row base within tensor (outputs)
    const float* bias = is_enc ? b1 : b2;
    const int woff = (is_enc ? 0 : 65536);

    const int r16 = lane & 15;
    const int kg8 = (lane >> 4) << 3;   // 0,8,16,24

    // staging coords (same mapping for A and B tiles)
    const int srow = tid >> 2, skoct = (tid & 3) << 3;

    f32x4 acc[2][2] = {};

    for (int kt = 0; kt < 256; kt += 32) {
        {   // A tile: rows rbf..rbf+63, k kt..kt+31 (16B coalesced loads)
            const int g = (rbf + srow) * 256 + kt + skoct;
            *reinterpret_cast<bf16x8*>(&Ah[srow][skoct]) =
                *reinterpret_cast<const bf16x8*>(&Xh[g]);
            *reinterpret_cast<bf16x8*>(&Al[srow][skoct]) =
                *reinterpret_cast<const bf16x8*>(&Xl[g]);
        }
        {   // B tile: u u0..u0+63, k kt..kt+31 from W^T planes
            const int g = woff + (u0 + srow) * 256 + kt + skoct;
            *reinterpret_cast<bf16x8*>(&Bh[srow][skoct]) =
                *reinterpret_cast<const bf16x8*>(&WTh[g]);
            *reinterpret_cast<bf16x8*>(&Bl[srow][skoct]) =
                *reinterpret_cast<const bf16x8*>(&WTl[g]);
        }
        __syncthreads();

        bf16x8 fah[2], fal[2], fbh[2], fbl[2];
        #pragma unroll
        for (int i = 0; i < 2; ++i) {
            const int ar = (wr << 5) + (i << 4) + r16;
            fah[i] = *reinterpret_cast<const bf16x8*>(&Ah[ar][kg8]);
            fal[i] = *reinterpret_cast<const bf16x8*>(&Al[ar][kg8]);
        }
        #pragma unroll
        for (int j = 0; j < 2; ++j) {
            const int wu = (wc << 5) + (j << 4) + r16;
            fbh[j] = *reinterpret_cast<const bf16x8*>(&Bh[wu][kg8]);
            fbl[j] = *reinterpret_cast<const bf16x8*>(&Bl[wu][kg8]);
        }
        #pragma unroll
        for (int i = 0; i < 2; ++i)
            #pragma unroll
            for (int j = 0; j < 2; ++j) {
                acc[i][j] = __builtin_amdgcn_mfma_f32_16x16x32_bf16(
                    fah[i], fbh[j], acc[i][j], 0, 0, 0);
                acc[i][j] = __builtin_amdgcn_mfma_f32_16x16x32_bf16(
                    fah[i], fbl[j], acc[i][j], 0, 0, 0);
                acc[i][j] = __builtin_amdgcn_mfma_f32_16x16x32_bf16(
                    fal[i], fbh[j], acc[i][j], 0, 0, 0);
            }
        __syncthreads();
    }

    // ---- epilogue: D[r][c] c=lane&15, r=(lane>>4)*4+reg
    const int kg = lane >> 4;
    float bb[2];
    #pragma unroll
    for (int j = 0; j < 2; ++j)
        bb[j] = bias[u0 + (wc << 5) + (j << 4) + r16];

    if (is_enc) {
        #pragma unroll
        for (int i = 0; i < 2; ++i)
            #pragma unroll
            for (int j = 0; j < 2; ++j) {
                const int gu = u0 + (wc << 5) + (j << 4) + r16;
                #pragma unroll
                for (int r = 0; r < 4; ++r) {
                    const int grow = rbt + (wr << 5) + (i << 4) + (kg << 2) + r;
                    const int b = grow >> 8, m = grow & 255;
                    const float val = __builtin_amdgcn_exp2f(
                        fmaf(KSC, acc[i][j][r] + bb[j], -16.f));
                    encQ[b * 65536 + (gu >> 2) * 1024 + (m << 2) + (gu & 3)] = val;
                }
            }
    } else {
        float rv[2];
        #pragma unroll
        for (int j = 0; j < 2; ++j)
            rv[j] = rcp_clamp(vw[u0 + (wc << 5) + (j << 4) + r16]);
        #pragma unroll
        for (int i = 0; i < 2; ++i)
            #pragma unroll
            for (int j = 0; j < 2; ++j) {
                const int gu = u0 + (wc << 5) + (j << 4) + r16;
                #pragma unroll
                for (int r = 0; r < 4; ++r) {
                    const int grow = rbt + (wr << 5) + (i << 4) + (kg << 2) + r;
                    const float val = __builtin_amdgcn_exp2f(
                        KSC * (acc[i][j][r] + bb[j])) * rv[j];
                    decE[grow * 256 + gu] = val;
                }
            }
    }
}

// ---------------- Kernel 2: logits. r7 body, m-split x2. 256 thr: h=tid>>7
// owns chains t0=4h..4h+3, m = (mh<<7)|(tid&127). Grid (32,16,2) = 1024 blocks.
__global__ __launch_bounds__(256) void logit_kernel(
    const float* __restrict__ encQ,  // [b][u/4][m][4] = exp2(K*ep-16)
    const float* __restrict__ decE,  // [n_flat][u]    = exp2(K*dp)*rcpc(v)
    const float* __restrict__ vw,    // [U]
    float* __restrict__ logits)      // [B][N][M] (= out_attn region)
{
    __shared__ float dsD[8][256];
    __shared__ float vcs[256];

    const int tid = threadIdx.x;     // 0..255
    const int b   = blockIdx.y;
    const int n0  = blockIdx.x << 3;
    const int mh  = blockIdx.z;
    const int h   = tid >> 7;
    const int m   = (mh << 7) | (tid & 127);
    const int t0  = h << 2;

    {   // stage decE rows n0..n0+7 and vcs = 2^-16 * rcpc(v)
        const float* dsrc = decE + (b * 256 + n0) * 256;
        #pragma unroll
        for (int i = 0; i < 8; ++i)
            ((float*)dsD)[tid + (i << 8)] = dsrc[tid + (i << 8)];
        vcs[tid] = S16 * rcp_clamp(vw[tid]);
    }
    __syncthreads();

    const float* ep = encQ + b * 65536 + (m << 2);
    F4 Ea = ld4(ep);
    F4 Eb = ld4(ep + 1024);
    ep += 2048;

    float acc[4] = {};

    #pragma unroll 4
    for (int o = 0; o < 32; ++o) {
        const F4 Ena = ld4(ep);      // always-prefetch; final read spills into
        const F4 Enb = ld4(ep + 1024);  // decE region (harmless)
        ep += 2048;
        const int u0 = o << 3;
        const F4 ca = ld4(&vcs[u0]);
        const F4 cb = ld4(&vcs[u0 + 4]);
        #pragma unroll
        for (int c = 0; c < 4; ++c) {
            const F4 da = ld4(&dsD[t0 + c][u0]);
            const F4 db = ld4(&dsD[t0 + c][u0 + 4]);
            const float z0 = fmaf(Ea.v[0], da.v[0], ca.v[0]);
            const float z1 = fmaf(Ea.v[1], da.v[1], ca.v[1]);
            const float z2 = fmaf(Ea.v[2], da.v[2], ca.v[2]);
            const float z3 = fmaf(Ea.v[3], da.v[3], ca.v[3]);
            const float y0 = fmaf(Eb.v[0], db.v[0], cb.v[0]);
            const float y1 = fmaf(Eb.v[1], db.v[1], cb.v[1]);
            const float y2 = fmaf(Eb.v[2], db.v[2], cb.v[2]);
            const float y3 = fmaf(Eb.v[3], db.v[3], cb.v[3]);
            const float pz01 = z0 * z1, pz23 = z2 * z3;
            const float py01 = y0 * y1, py23 = y2 * y3;
            const float nz = fmaf(z0 + z1, pz23, (z2 + z3) * pz01);
            const float ny = fmaf(y0 + y1, py23, (y2 + y3) * py01);
            const float pz = pz01 * pz23, py = py01 * py23;
            const float num = fmaf(nz, py, ny * pz);
            acc[c] = fmaf(num, __builtin_amdgcn_rcpf(pz * py), acc[c]);
        }
        Ea = Ena; Eb = Enb;
    }

    #pragma unroll
    for (int c = 0; c < 4; ++c)
        logits[(b * 256 + n0 + t0 + c) * 256 + m] = acc[c] * LSC;
}

// ---------------- Kernel 3: softmax + context (r7 VERBATIM). 512 thr. Grid (32,16).
__global__ __launch_bounds__(512) void smctx_kernel(
    const float* __restrict__ enc,   // [B][M][D]
    float* __restrict__ out_attn,    // in: logits, out: weights
    float* __restrict__ out_ctx)     // [B][N][D]
{
    __shared__ float attn_s[8][256];
    __shared__ float redm[8][4], reds[8][4];

    const int tid = threadIdx.x;     // 0..511
    const int b   = blockIdx.y;
    const int n0  = blockIdx.x << 3;
    const int h   = tid >> 8;
    const int m   = tid & 255;
    const int t0  = h << 2;

    float l[4];
    #pragma unroll
    for (int c = 0; c < 4; ++c)
        l[c] = out_attn[(b * 256 + n0 + t0 + c) * 256 + m];

    const int lane = tid & 63, wq = (tid >> 6) & 3;
    #pragma unroll
    for (int c = 0; c < 4; ++c) {
        float x = l[c];
        #pragma unroll
        for (int off = 32; off > 0; off >>= 1)
            x = fmaxf(x, __shfl_xor(x, off));
        if (lane == 0) redm[t0 + c][wq] = x;
    }
    __syncthreads();
    float p[4];
    #pragma unroll
    for (int c = 0; c < 4; ++c) {
        const float mx = fmaxf(fmaxf(redm[t0 + c][0], redm[t0 + c][1]),
                               fmaxf(redm[t0 + c][2], redm[t0 + c][3]));
        p[c] = __builtin_amdgcn_exp2f((l[c] - mx) * LOG2E);
    }
    #pragma unroll
    for (int c = 0; c < 4; ++c) {
        float x = p[c];
        #pragma unroll
        for (int off = 32; off > 0; off >>= 1)
            x += __shfl_xor(x, off);
        if (lane == 0) reds[t0 + c][wq] = x;
    }
    __syncthreads();
    #pragma unroll
    for (int c = 0; c < 4; ++c) {
        const float s = (reds[t0 + c][0] + reds[t0 + c][1])
                      + (reds[t0 + c][2] + reds[t0 + c][3]);
        const float w = p[c] * __builtin_amdgcn_rcpf(s);
        attn_s[t0 + c][m] = w;
        out_attn[(b * 256 + n0 + t0 + c) * 256 + m] = w;
    }
    __syncthreads();

    const float* eb = enc + b * 65536 + m;
    float cx[4] = {};
    #pragma unroll 4
    for (int mm = 0; mm < 256; mm += 4) {
        const float g0 = eb[(mm + 0) << 8];
        const float g1 = eb[(mm + 1) << 8];
        const float g2 = eb[(mm + 2) << 8];
        const float g3 = eb[(mm + 3) << 8];
        #pragma unroll
        for (int c = 0; c < 4; ++c) {
            const F4 aq = ld4(&attn_s[t0 + c][mm]);
            cx[c] = fmaf(aq.v[0], g0, cx[c]);
            cx[c] = fmaf(aq.v[1], g1, cx[c]);
            cx[c] = fmaf(aq.v[2], g2, cx[c]);
            cx[c] = fmaf(aq.v[3], g3, cx[c]);
        }
    }
    #pragma unroll
    for (int c = 0; c < 4; ++c)
        out_ctx[(b * 256 + n0 + t0 + c) * 256 + m] = cx[c];
}

extern "C" void kernel_launch(void* const* d_in, const int* in_sizes, int n_in,
                              void* d_out, int out_size, void* d_ws, size_t ws_size,
                              hipStream_t stream) {
    const float* enc = (const float*)d_in[0];
    const float* dec = (const float*)d_in[1];
    const float* W1  = (const float*)d_in[2];
    const float* b1  = (const float*)d_in[3];
    const float* W2  = (const float*)d_in[4];
    const float* b2  = (const float*)d_in[5];
    const float* vw  = (const float*)d_in[6];
    // d_in[7] (v_b) cancels in softmax — unused.

    float* out_ctx  = (float*)d_out;
    float* out_attn = (float*)d_out + 16 * 256 * 256;

    float* encQ = (float*)d_ws;                   // 4 MB
    float* decE = encQ + 2097152 / 2;             // +1M floats = 4 MB
    short* Xh   = (short*)(encQ + 2097152);       // 4 MB (2M shorts)
    short* Xl   = Xh + 2097152;                   // 4 MB
    short* WTh  = Xl + 2097152;                   // 256 KB
    short* WTl  = WTh + 131072;                   // 256 KB

    split_kernel<<<dim3(8704),      256, 0, stream>>>(enc, dec, W1, W2, Xh, Xl, WTh, WTl);
    proj_kernel <<<dim3(4, 128),    256, 0, stream>>>(Xh, Xl, WTh, WTl, b1, b2, vw, encQ, decE);
    logit_kernel<<<dim3(32, 16, 2), 256, 0, stream>>>(encQ, decE, vw, out_attn);
    smctx_kernel<<<dim3(32, 16),    512, 0, stream>>>(enc, out_attn, out_ctx);
}